// Round 5
// baseline (232.986 us; speedup 1.0000x reference)
//
#include <hip/hip_runtime.h>
#include <math.h>

#define BATCHN 65536
#define INPUTN 128
#define HIDDENN 512
#define CATN 640
#define ROWS_LSTM 32

// ---------------------------------------------------------------------------
// Kernel 0: build the fixed 16x16 unitary U_g per gate (batch-independent part
// of the circuit). Thread t = (g<<4)|col simulates basis state |col>.
// ---------------------------------------------------------------------------
__global__ void k_build_u(const float* __restrict__ qwF, const float* __restrict__ qwI,
                          const float* __restrict__ qwO, const float* __restrict__ qwC,
                          float2* __restrict__ U) {
  int t = threadIdx.x;
  if (t >= 64) return;
  int g = t >> 4, col = t & 15;
  const float* qw = (g == 0) ? qwF : (g == 1) ? qwI : (g == 2) ? qwO : qwC;

  float sr[16], si[16];
#pragma unroll
  for (int i = 0; i < 16; i++) { sr[i] = (i == col) ? 1.f : 0.f; si[i] = 0.f; }

#pragma unroll
  for (int l = 0; l < 2; l++) {
#pragma unroll
    for (int j = 0; j < 4; j++) {
      const int bc = 8 >> j;
      const int bt = 8 >> ((j + 1) & 3);
      float tr[16], ti[16];
#pragma unroll
      for (int i = 0; i < 16; i++) {
        int src = (i & bc) ? (i ^ bt) : i;
        tr[i] = sr[src]; ti[i] = si[src];
      }
#pragma unroll
      for (int i = 0; i < 16; i++) { sr[i] = tr[i]; si[i] = ti[i]; }
    }
#pragma unroll
    for (int j = 0; j < 4; j++) {
      const int bit = 8 >> j;
      const float thx = qw[(l * 4 + j) * 3 + 0] * 0.5f;
      const float thy = qw[(l * 4 + j) * 3 + 1] * 0.5f;
      const float thz = qw[(l * 4 + j) * 3 + 2] * 0.5f;
      float c, s;
      c = cosf(thx); s = sinf(thx);           // RX
#pragma unroll
      for (int i = 0; i < 16; i++) if (!(i & bit)) {
        const int k2 = i | bit;
        const float ar = sr[i], ai = si[i], br = sr[k2], bi = si[k2];
        sr[i]  = c * ar + s * bi;  si[i]  = c * ai - s * br;
        sr[k2] = c * br + s * ai;  si[k2] = c * bi - s * ar;
      }
      c = cosf(thy); s = sinf(thy);           // RY
#pragma unroll
      for (int i = 0; i < 16; i++) if (!(i & bit)) {
        const int k2 = i | bit;
        const float ar = sr[i], ai = si[i], br = sr[k2], bi = si[k2];
        sr[i]  = c * ar - s * br;  si[i]  = c * ai - s * bi;
        sr[k2] = s * ar + c * br;  si[k2] = s * ai + c * bi;
      }
      c = cosf(thz); s = sinf(thz);           // RZ
#pragma unroll
      for (int i = 0; i < 16; i++) if (!(i & bit)) {
        const int k2 = i | bit;
        const float ar = sr[i], ai = si[i], br = sr[k2], bi = si[k2];
        sr[i]  = c * ar + s * ai;  si[i]  = c * ai - s * ar;
        sr[k2] = c * br - s * bi;  si[k2] = c * bi + s * br;
      }
    }
  }
#pragma unroll
  for (int m = 0; m < 16; m++)
    U[(g * 16 + m) * 16 + col] = make_float2(sr[m], si[m]);
}

// ---------------------------------------------------------------------------
// Kernel 1: block = 64 rows, 4 waves. Wave w accumulates ALL 16 gate-outputs
// over K-segment x[32w,32w+32) + h[128w,128w+128) with direct per-lane row
// streaming (each 64B line fully consumed by 4 consecutive loads of one lane).
// Weight addresses are wave-uniform -> scalar K$ loads. NO barriers / vmcnt
// drains in the main loop. One barrier: partials via LDS [4][64][20], then
// wave w runs the quantum sim for gate w (balanced tail).
// ---------------------------------------------------------------------------
__global__ __launch_bounds__(256) void k_proj_q(
    const float* __restrict__ x, const float* __restrict__ hprev,
    const float* __restrict__ pwF, const float* __restrict__ pbF,
    const float* __restrict__ pwI, const float* __restrict__ pbI,
    const float* __restrict__ pwO, const float* __restrict__ pbO,
    const float* __restrict__ pwC, const float* __restrict__ pbC,
    const float2* __restrict__ U, float* __restrict__ qv) {
  __shared__ float part[4][64][20];
  const int tid = threadIdx.x;
  const int w = tid >> 6;           // wave id = K-segment id = tail gate id
  const int r = tid & 63;           // row within block
  const size_t row = (size_t)blockIdx.x * 64 + r;

  float acc[16];
#pragma unroll
  for (int j = 0; j < 16; j++) acc[j] = 0.f;

  const float* xr = x + row * INPUTN + w * 32;
  const float* hr = hprev + row * HIDDENN + w * 128;

  // x segment: 8 float4 steps, weight col = w*32 + s*4
#pragma unroll 4
  for (int s = 0; s < 8; ++s) {
    const float4 a = *(const float4*)(xr + s * 4);
    const int k = w * 32 + s * 4;
#pragma unroll
    for (int j = 0; j < 4; j++) {
      const float4 wf = *(const float4*)(pwF + j * CATN + k);
      const float4 wi = *(const float4*)(pwI + j * CATN + k);
      const float4 wo = *(const float4*)(pwO + j * CATN + k);
      const float4 wc = *(const float4*)(pwC + j * CATN + k);
      acc[0  + j] += a.x * wf.x + a.y * wf.y + a.z * wf.z + a.w * wf.w;
      acc[4  + j] += a.x * wi.x + a.y * wi.y + a.z * wi.z + a.w * wi.w;
      acc[8  + j] += a.x * wo.x + a.y * wo.y + a.z * wo.z + a.w * wo.w;
      acc[12 + j] += a.x * wc.x + a.y * wc.y + a.z * wc.z + a.w * wc.w;
    }
  }
  // h segment: 32 float4 steps, weight col = 128 + w*128 + s*4
#pragma unroll 4
  for (int s = 0; s < 32; ++s) {
    const float4 a = *(const float4*)(hr + s * 4);
    const int k = INPUTN + w * 128 + s * 4;
#pragma unroll
    for (int j = 0; j < 4; j++) {
      const float4 wf = *(const float4*)(pwF + j * CATN + k);
      const float4 wi = *(const float4*)(pwI + j * CATN + k);
      const float4 wo = *(const float4*)(pwO + j * CATN + k);
      const float4 wc = *(const float4*)(pwC + j * CATN + k);
      acc[0  + j] += a.x * wf.x + a.y * wf.y + a.z * wf.z + a.w * wf.w;
      acc[4  + j] += a.x * wi.x + a.y * wi.y + a.z * wi.z + a.w * wi.w;
      acc[8  + j] += a.x * wo.x + a.y * wo.y + a.z * wo.z + a.w * wo.w;
      acc[12 + j] += a.x * wc.x + a.y * wc.y + a.z * wc.z + a.w * wc.w;
    }
  }

  // publish partial sums
#pragma unroll
  for (int j4 = 0; j4 < 4; ++j4)
    *(float4*)&part[w][r][j4 * 4] =
        make_float4(acc[j4 * 4], acc[j4 * 4 + 1], acc[j4 * 4 + 2], acc[j4 * 4 + 3]);
  __syncthreads();

  // wave w: combine partials for gate w, row r
  const float* pbg = (w == 0) ? pbF : (w == 1) ? pbI : (w == 2) ? pbO : pbC;
  float ang0 = pbg[0], ang1 = pbg[1], ang2 = pbg[2], ang3 = pbg[3];
#pragma unroll
  for (int s = 0; s < 4; ++s) {
    const float4 p = *(const float4*)&part[s][r][w * 4];
    ang0 += p.x; ang1 += p.y; ang2 += p.z; ang3 += p.w;
  }

  // quantum sim for gate w
  float ang[4] = {ang0, ang1, ang2, ang3};
  float cs[4], sn[4];
#pragma unroll
  for (int j = 0; j < 4; j++) __sincosf(ang[j] * 0.5f, &sn[j], &cs[j]);
  float psi[16];
#pragma unroll
  for (int c16 = 0; c16 < 16; c16++) {
    float p = ((c16 & 8) ? sn[0] : cs[0]);
    p *= ((c16 & 4) ? sn[1] : cs[1]);
    p *= ((c16 & 2) ? sn[2] : cs[2]);
    p *= ((c16 & 1) ? sn[3] : cs[3]);
    psi[c16] = p;
  }
  const float2* Ug = U + w * 256;
  float q0 = 0.f, q1 = 0.f, q2 = 0.f, q3 = 0.f;
#pragma unroll
  for (int m = 0; m < 16; m++) {
    float ssr = 0.f, ssi = 0.f;
#pragma unroll
    for (int c16 = 0; c16 < 16; c16++) {
      const float2 u = Ug[m * 16 + c16];
      ssr += u.x * psi[c16];
      ssi += u.y * psi[c16];
    }
    const float p = ssr * ssr + ssi * ssi;
    q0 = (m & 8) ? q0 - p : q0 + p;
    q1 = (m & 4) ? q1 - p : q1 + p;
    q2 = (m & 2) ? q2 - p : q2 + p;
    q3 = (m & 1) ? q3 - p : q3 + p;
  }
  *(float4*)(qv + row * 16 + w * 4) = make_float4(q0, q1, q2, q3);
}

// ---------------------------------------------------------------------------
// Kernel 2: LSTM expansion. Thread owns h-positions {tid, tid+256}; weights/
// biases in registers (coalesced setup), streaming c_prev/out accesses are
// coalesced and nontemporal.
// ---------------------------------------------------------------------------
__device__ __forceinline__ float sigmf(float v) {
  return __builtin_amdgcn_rcpf(1.f + __expf(-v));
}
__device__ __forceinline__ float tanhfast(float v) {
  return 1.f - 2.f * __builtin_amdgcn_rcpf(__expf(2.f * v) + 1.f);
}

__global__ __launch_bounds__(256) void k_lstm(
    const float* __restrict__ qv, const float* __restrict__ cprev,
    const float* __restrict__ lwF, const float* __restrict__ lbF,
    const float* __restrict__ lwI, const float* __restrict__ lbI,
    const float* __restrict__ lwO, const float* __restrict__ lbO,
    const float* __restrict__ lwC, const float* __restrict__ lbC,
    float* __restrict__ out) {
  const int tid = threadIdx.x;
  const int rb = blockIdx.x * ROWS_LSTM;

  float4 wF[2], wI[2], wO[2], wC[2];
  float bFv[2], bIv[2], bOv[2], bCv[2];
#pragma unroll
  for (int hh = 0; hh < 2; ++hh) {
    const int hp = tid + hh * 256;
    wF[hh] = *(const float4*)(lwF + (size_t)hp * 4);
    wI[hh] = *(const float4*)(lwI + (size_t)hp * 4);
    wO[hh] = *(const float4*)(lwO + (size_t)hp * 4);
    wC[hh] = *(const float4*)(lwC + (size_t)hp * 4);
    bFv[hh] = lbF[hp]; bIv[hh] = lbI[hp]; bOv[hh] = lbO[hp]; bCv[hh] = lbC[hp];
  }

#pragma unroll 2
  for (int it = 0; it < ROWS_LSTM; ++it) {
    const int r = rb + it;
    const float* q = qv + (size_t)r * 16;     // block-uniform -> scalar loads
    const float4 qF = *(const float4*)(q);
    const float4 qI = *(const float4*)(q + 4);
    const float4 qO = *(const float4*)(q + 8);
    const float4 qC = *(const float4*)(q + 12);

#pragma unroll
    for (int hh = 0; hh < 2; ++hh) {
      const int hp = tid + hh * 256;
      const float cp = __builtin_nontemporal_load(cprev + (size_t)r * HIDDENN + hp);
      const float pf = bFv[hh] + wF[hh].x * qF.x + wF[hh].y * qF.y + wF[hh].z * qF.z + wF[hh].w * qF.w;
      const float pi = bIv[hh] + wI[hh].x * qI.x + wI[hh].y * qI.y + wI[hh].z * qI.z + wI[hh].w * qI.w;
      const float po = bOv[hh] + wO[hh].x * qO.x + wO[hh].y * qO.y + wO[hh].z * qO.z + wO[hh].w * qO.w;
      const float pg = bCv[hh] + wC[hh].x * qC.x + wC[hh].y * qC.y + wC[hh].z * qC.z + wC[hh].w * qC.w;
      const float f  = sigmf(pf);
      const float ii = sigmf(pi);
      const float oo = sigmf(po);
      const float gg = tanhfast(pg);
      const float cc = f * cp + ii * gg;
      __builtin_nontemporal_store(oo * tanhfast(cc), out + (size_t)r * HIDDENN + hp);
      __builtin_nontemporal_store(cc, out + (size_t)BATCHN * HIDDENN + (size_t)r * HIDDENN + hp);
    }
  }
}

// ---------------------------------------------------------------------------
extern "C" void kernel_launch(void* const* d_in, const int* in_sizes, int n_in,
                              void* d_out, int out_size, void* d_ws, size_t ws_size,
                              hipStream_t stream) {
  const float* x  = (const float*)d_in[0];
  const float* h  = (const float*)d_in[1];
  const float* c  = (const float*)d_in[2];
  const float* pwF = (const float*)d_in[3];
  const float* pbF = (const float*)d_in[4];
  const float* qwF = (const float*)d_in[5];
  const float* lwF = (const float*)d_in[6];
  const float* lbF = (const float*)d_in[7];
  const float* pwI = (const float*)d_in[8];
  const float* pbI = (const float*)d_in[9];
  const float* qwI = (const float*)d_in[10];
  const float* lwI = (const float*)d_in[11];
  const float* lbI = (const float*)d_in[12];
  const float* pwO = (const float*)d_in[13];
  const float* pbO = (const float*)d_in[14];
  const float* qwO = (const float*)d_in[15];
  const float* lwO = (const float*)d_in[16];
  const float* lbO = (const float*)d_in[17];
  const float* pwC = (const float*)d_in[18];
  const float* pbC = (const float*)d_in[19];
  const float* qwC = (const float*)d_in[20];
  const float* lwC = (const float*)d_in[21];
  const float* lbC = (const float*)d_in[22];

  float* ws = (float*)d_ws;
  float* qv = ws;                                  // BATCHN*16 floats (4 MB)
  float2* U = (float2*)(ws + (size_t)BATCHN * 16); // 4*16*16 float2 (8 KB)

  k_build_u<<<dim3(1), dim3(64), 0, stream>>>(qwF, qwI, qwO, qwC, U);
  k_proj_q<<<dim3(BATCHN / 64), dim3(256), 0, stream>>>(x, h, pwF, pbF, pwI, pbI,
                                                        pwO, pbO, pwC, pbC, U, qv);
  k_lstm<<<dim3(BATCHN / ROWS_LSTM), dim3(256), 0, stream>>>(qv, c, lwF, lbF, lwI, lbI,
                                                             lwO, lbO, lwC, lbC,
                                                             (float*)d_out);
}

// Round 7
// 163.467 us; speedup vs baseline: 1.4253x; 1.4253x over previous
//
#include <hip/hip_runtime.h>
#include <math.h>

#define BATCHN 65536
#define INPUTN 128
#define HIDDENN 512
#define CATN 640
#define ROWS_LSTM 32

typedef float f2v __attribute__((ext_vector_type(2)));

// ---------------------------------------------------------------------------
// Kernel 0: build the fixed 16x16 unitary U_g per gate (batch-independent part
// of the circuit). Thread t = (g<<4)|col simulates basis state |col>.
// ---------------------------------------------------------------------------
__global__ void k_build_u(const float* __restrict__ qwF, const float* __restrict__ qwI,
                          const float* __restrict__ qwO, const float* __restrict__ qwC,
                          float2* __restrict__ U) {
  int t = threadIdx.x;
  if (t >= 64) return;
  int g = t >> 4, col = t & 15;
  const float* qw = (g == 0) ? qwF : (g == 1) ? qwI : (g == 2) ? qwO : qwC;

  float sr[16], si[16];
#pragma unroll
  for (int i = 0; i < 16; i++) { sr[i] = (i == col) ? 1.f : 0.f; si[i] = 0.f; }

#pragma unroll
  for (int l = 0; l < 2; l++) {
#pragma unroll
    for (int j = 0; j < 4; j++) {
      const int bc = 8 >> j;
      const int bt = 8 >> ((j + 1) & 3);
      float tr[16], ti[16];
#pragma unroll
      for (int i = 0; i < 16; i++) {
        int src = (i & bc) ? (i ^ bt) : i;
        tr[i] = sr[src]; ti[i] = si[src];
      }
#pragma unroll
      for (int i = 0; i < 16; i++) { sr[i] = tr[i]; si[i] = ti[i]; }
    }
#pragma unroll
    for (int j = 0; j < 4; j++) {
      const int bit = 8 >> j;
      const float thx = qw[(l * 4 + j) * 3 + 0] * 0.5f;
      const float thy = qw[(l * 4 + j) * 3 + 1] * 0.5f;
      const float thz = qw[(l * 4 + j) * 3 + 2] * 0.5f;
      float c, s;
      c = cosf(thx); s = sinf(thx);           // RX
#pragma unroll
      for (int i = 0; i < 16; i++) if (!(i & bit)) {
        const int k2 = i | bit;
        const float ar = sr[i], ai = si[i], br = sr[k2], bi = si[k2];
        sr[i]  = c * ar + s * bi;  si[i]  = c * ai - s * br;
        sr[k2] = c * br + s * ai;  si[k2] = c * bi - s * ar;
      }
      c = cosf(thy); s = sinf(thy);           // RY
#pragma unroll
      for (int i = 0; i < 16; i++) if (!(i & bit)) {
        const int k2 = i | bit;
        const float ar = sr[i], ai = si[i], br = sr[k2], bi = si[k2];
        sr[i]  = c * ar - s * br;  si[i]  = c * ai - s * bi;
        sr[k2] = s * ar + c * br;  si[k2] = s * ai + c * bi;
      }
      c = cosf(thz); s = sinf(thz);           // RZ
#pragma unroll
      for (int i = 0; i < 16; i++) if (!(i & bit)) {
        const int k2 = i | bit;
        const float ar = sr[i], ai = si[i], br = sr[k2], bi = si[k2];
        sr[i]  = c * ar + s * ai;  si[i]  = c * ai - s * ar;
        sr[k2] = c * br - s * bi;  si[k2] = c * bi + s * br;
      }
    }
  }
#pragma unroll
  for (int m = 0; m < 16; m++)
    U[(g * 16 + m) * 16 + col] = make_float2(sr[m], si[m]);
}

// ---------------------------------------------------------------------------
// Kernel 1 (v6): block = 64 rows x 4 waves. Wave w owns K-segment
// [160w, 160w+160). All 4 gates' projection weights are staged into LDS once
// (wave w stages gate w, coalesced); main-loop weight reads are broadcast
// ds_reads (same address across lanes) -- no per-thread global weight loads,
// no barriers in the main loop. Partials combined through the (then-dead)
// weight LDS region; wave w runs the quantum sim for gate w.
// ---------------------------------------------------------------------------
__global__ __launch_bounds__(256) void k_proj_q(
    const float* __restrict__ x, const float* __restrict__ hprev,
    const float* __restrict__ pwF, const float* __restrict__ pbF,
    const float* __restrict__ pwI, const float* __restrict__ pbI,
    const float* __restrict__ pwO, const float* __restrict__ pbO,
    const float* __restrict__ pwC, const float* __restrict__ pbC,
    const float2* __restrict__ U, float* __restrict__ qv) {
  __shared__ float4 smem[2560];     // 40 KB weights [gate][4][160]; reused for partials
  const int tid = threadIdx.x;
  const int w = tid >> 6;           // wave id = K-segment id = tail gate id
  const int l = tid & 63;           // row within block / lane
  const size_t row = (size_t)blockIdx.x * 64 + l;

  // stage gate w's weights: 640 float4, coalesced (lane l takes l + i*64)
  const float* pwg = (w == 0) ? pwF : (w == 1) ? pwI : (w == 2) ? pwO : pwC;
#pragma unroll
  for (int i = 0; i < 10; ++i)
    smem[w * 640 + l + i * 64] = ((const float4*)pwg)[l + i * 64];
  __syncthreads();

  float acc[16];
#pragma unroll
  for (int j = 0; j < 16; j++) acc[j] = 0.f;

  // one k-step: a = 4 row elements at segment-step ss; 16 broadcast ds_reads
  auto kstep = [&](int ss, float4 a) {
#pragma unroll
    for (int g = 0; g < 4; ++g)
#pragma unroll
      for (int o = 0; o < 4; ++o) {
        const float4 wv = smem[g * 640 + o * 160 + w * 40 + ss];
        acc[g * 4 + o] += a.x * wv.x + a.y * wv.y + a.z * wv.z + a.w * wv.w;
      }
  };

  if (w == 0) {   // segment 0: x[0..128) then h[0..32)
    const float* xr = x + row * INPUTN;
#pragma unroll 8
    for (int ss = 0; ss < 32; ++ss) kstep(ss, *(const float4*)(xr + ss * 4));
    const float* hr = hprev + row * HIDDENN;
#pragma unroll
    for (int ss = 32; ss < 40; ++ss) kstep(ss, *(const float4*)(hr + (ss - 32) * 4));
  } else {        // segments 1..3: pure h
    const float* hr = hprev + row * HIDDENN + (w * 160 - INPUTN);
#pragma unroll 8
    for (int ss = 0; ss < 40; ++ss) kstep(ss, *(const float4*)(hr + ss * 4));
  }

  // publish partials into the (now dead) weight LDS: part[4][64][20]
  __syncthreads();                    // everyone done reading weights
  float* part = (float*)smem;
#pragma unroll
  for (int j4 = 0; j4 < 4; ++j4)
    *(float4*)&part[(w * 64 + l) * 20 + j4 * 4] =
        make_float4(acc[j4 * 4], acc[j4 * 4 + 1], acc[j4 * 4 + 2], acc[j4 * 4 + 3]);
  __syncthreads();

  // wave w: combine partials for gate w, row l
  const float* pbg = (w == 0) ? pbF : (w == 1) ? pbI : (w == 2) ? pbO : pbC;
  float ang[4] = {pbg[0], pbg[1], pbg[2], pbg[3]};
#pragma unroll
  for (int s = 0; s < 4; ++s) {
    const float4 p = *(const float4*)&part[(s * 64 + l) * 20 + w * 4];
    ang[0] += p.x; ang[1] += p.y; ang[2] += p.z; ang[3] += p.w;
  }

  // quantum sim for gate w
  float cs[4], sn[4];
#pragma unroll
  for (int j = 0; j < 4; j++) __sincosf(ang[j] * 0.5f, &sn[j], &cs[j]);
  float psi[16];
#pragma unroll
  for (int c16 = 0; c16 < 16; c16++) {
    float p = ((c16 & 8) ? sn[0] : cs[0]);
    p *= ((c16 & 4) ? sn[1] : cs[1]);
    p *= ((c16 & 2) ? sn[2] : cs[2]);
    p *= ((c16 & 1) ? sn[3] : cs[3]);
    psi[c16] = p;
  }
  const float2* Ug = U + w * 256;
  float q0 = 0.f, q1 = 0.f, q2 = 0.f, q3 = 0.f;
#pragma unroll
  for (int m = 0; m < 16; m++) {
    float ssr = 0.f, ssi = 0.f;
#pragma unroll
    for (int c16 = 0; c16 < 16; c16++) {
      const float2 u = Ug[m * 16 + c16];
      ssr += u.x * psi[c16];
      ssi += u.y * psi[c16];
    }
    const float p = ssr * ssr + ssi * ssi;
    q0 = (m & 8) ? q0 - p : q0 + p;
    q1 = (m & 4) ? q1 - p : q1 + p;
    q2 = (m & 2) ? q2 - p : q2 + p;
    q3 = (m & 1) ? q3 - p : q3 + p;
  }
  *(float4*)(qv + row * 16 + w * 4) = make_float4(q0, q1, q2, q3);
}

// ---------------------------------------------------------------------------
// Kernel 2: LSTM expansion. Thread owns 2 CONSECUTIVE h-positions -> float2
// streaming accesses (half the VMEM instructions of the scalar version).
// Weights/biases register-resident; q block-uniform -> scalar loads.
// Nontemporal accesses use a native ext_vector type (builtin rejects
// HIP_vector_type).
// ---------------------------------------------------------------------------
__device__ __forceinline__ float sigmf(float v) {
  return __builtin_amdgcn_rcpf(1.f + __expf(-v));
}
__device__ __forceinline__ float tanhfast(float v) {
  return 1.f - 2.f * __builtin_amdgcn_rcpf(__expf(2.f * v) + 1.f);
}

__global__ __launch_bounds__(256) void k_lstm(
    const float* __restrict__ qv, const float* __restrict__ cprev,
    const float* __restrict__ lwF, const float* __restrict__ lbF,
    const float* __restrict__ lwI, const float* __restrict__ lbI,
    const float* __restrict__ lwO, const float* __restrict__ lbO,
    const float* __restrict__ lwC, const float* __restrict__ lbC,
    float* __restrict__ out) {
  const int tid = threadIdx.x;
  const int h0 = tid * 2;               // 2 consecutive h-positions
  const int rb = blockIdx.x * ROWS_LSTM;

  float4 wF[2], wI[2], wO[2], wC[2];
  float bFv[2], bIv[2], bOv[2], bCv[2];
#pragma unroll
  for (int hh = 0; hh < 2; ++hh) {
    const int hp = h0 + hh;
    wF[hh] = *(const float4*)(lwF + (size_t)hp * 4);
    wI[hh] = *(const float4*)(lwI + (size_t)hp * 4);
    wO[hh] = *(const float4*)(lwO + (size_t)hp * 4);
    wC[hh] = *(const float4*)(lwC + (size_t)hp * 4);
    bFv[hh] = lbF[hp]; bIv[hh] = lbI[hp]; bOv[hh] = lbO[hp]; bCv[hh] = lbC[hp];
  }

#pragma unroll 2
  for (int it = 0; it < ROWS_LSTM; ++it) {
    const int r = rb + it;
    const float* q = qv + (size_t)r * 16;     // block-uniform -> scalar loads
    const float4 qF = *(const float4*)(q);
    const float4 qI = *(const float4*)(q + 4);
    const float4 qO = *(const float4*)(q + 8);
    const float4 qC = *(const float4*)(q + 12);

    const f2v cp = __builtin_nontemporal_load(
        (const f2v*)(cprev + (size_t)r * HIDDENN + h0));
    float hn[2], cn[2];
#pragma unroll
    for (int hh = 0; hh < 2; ++hh) {
      const float pf = bFv[hh] + wF[hh].x * qF.x + wF[hh].y * qF.y + wF[hh].z * qF.z + wF[hh].w * qF.w;
      const float pi = bIv[hh] + wI[hh].x * qI.x + wI[hh].y * qI.y + wI[hh].z * qI.z + wI[hh].w * qI.w;
      const float po = bOv[hh] + wO[hh].x * qO.x + wO[hh].y * qO.y + wO[hh].z * qO.z + wO[hh].w * qO.w;
      const float pg = bCv[hh] + wC[hh].x * qC.x + wC[hh].y * qC.y + wC[hh].z * qC.z + wC[hh].w * qC.w;
      const float f  = sigmf(pf);
      const float ii = sigmf(pi);
      const float oo = sigmf(po);
      const float gg = tanhfast(pg);
      const float cc = f * cp[hh] + ii * gg;
      cn[hh] = cc;
      hn[hh] = oo * tanhfast(cc);
    }
    f2v hv; hv[0] = hn[0]; hv[1] = hn[1];
    f2v cv; cv[0] = cn[0]; cv[1] = cn[1];
    __builtin_nontemporal_store(hv, (f2v*)(out + (size_t)r * HIDDENN + h0));
    __builtin_nontemporal_store(cv,
        (f2v*)(out + (size_t)BATCHN * HIDDENN + (size_t)r * HIDDENN + h0));
  }
}

// ---------------------------------------------------------------------------
extern "C" void kernel_launch(void* const* d_in, const int* in_sizes, int n_in,
                              void* d_out, int out_size, void* d_ws, size_t ws_size,
                              hipStream_t stream) {
  const float* x  = (const float*)d_in[0];
  const float* h  = (const float*)d_in[1];
  const float* c  = (const float*)d_in[2];
  const float* pwF = (const float*)d_in[3];
  const float* pbF = (const float*)d_in[4];
  const float* qwF = (const float*)d_in[5];
  const float* lwF = (const float*)d_in[6];
  const float* lbF = (const float*)d_in[7];
  const float* pwI = (const float*)d_in[8];
  const float* pbI = (const float*)d_in[9];
  const float* qwI = (const float*)d_in[10];
  const float* lwI = (const float*)d_in[11];
  const float* lbI = (const float*)d_in[12];
  const float* pwO = (const float*)d_in[13];
  const float* pbO = (const float*)d_in[14];
  const float* qwO = (const float*)d_in[15];
  const float* lwO = (const float*)d_in[16];
  const float* lbO = (const float*)d_in[17];
  const float* pwC = (const float*)d_in[18];
  const float* pbC = (const float*)d_in[19];
  const float* qwC = (const float*)d_in[20];
  const float* lwC = (const float*)d_in[21];
  const float* lbC = (const float*)d_in[22];

  float* ws = (float*)d_ws;
  float* qv = ws;                                  // BATCHN*16 floats (4 MB)
  float2* U = (float2*)(ws + (size_t)BATCHN * 16); // 4*16*16 float2 (8 KB)

  k_build_u<<<dim3(1), dim3(64), 0, stream>>>(qwF, qwI, qwO, qwC, U);
  k_proj_q<<<dim3(BATCHN / 64), dim3(256), 0, stream>>>(x, h, pwF, pbF, pwI, pbI,
                                                        pwO, pbO, pwC, pbC, U, qv);
  k_lstm<<<dim3(BATCHN / ROWS_LSTM), dim3(256), 0, stream>>>(qv, c, lwF, lbF, lwI, lbI,
                                                             lwO, lbO, lwC, lbC,
                                                             (float*)d_out);
}